// Round 6
// baseline (1003.980 us; speedup 1.0000x reference)
//
#include <hip/hip_runtime.h>
#include <hip/hip_bf16.h>
#include <math.h>

#define TAU 0.5f
#define RPB 512        // rows per coarse bin (pass1 bin target, pass2 sort range)
#define SST2 2048      // segment stride (entries): 16 KB; cap = stride (2x mean fill)
#define STAGE_CAP 9216 // pass2 LDS stage entries (mean total 8163, +11.6 sigma)

// ---------------------------------------------------------------------------
// CSR build v4: COARSE XCD-local binning (3136 segments; write tips ~50KB/XCD
// -> L2-resident -> write-amp ~1x, vs v3's 25008 fine segments = 6.4MB/XCD >
// 4MB L2 = 5.3x write-amp, 136MB WRITE_SIZE, 163us). Fine 512-row sort moved
// into an upscaled place pass (74KB LDS stage per block).
// ---------------------------------------------------------------------------
__global__ void init_kernel(int* __restrict__ cur, float* __restrict__ norms,
                            int K, int NN) {
    int k = blockIdx.x * 256 + threadIdx.x;
    if (k < K) cur[k] = k * SST2;
    if (k < NN) norms[k] = 0.f;
}

__global__ void bin2_kernel(const int* __restrict__ rowA, const int* __restrict__ colA,
                            const float* __restrict__ valA,
                            const int* __restrict__ rowL, const int* __restrict__ colL,
                            const float* __restrict__ valL,
                            int* __restrict__ cur, int2* __restrict__ tmp,
                            int E, int eblocks, int NBC) {
    // HW_REG_XCC_ID (id=20, offset 0, size 32): imm = (31<<11)|20 = 63508.
    int xcd = __builtin_amdgcn_s_getreg(63508) & 7;
    int b = blockIdx.x;
    const int* row;
    const int* col;
    const float* val;
    int kbase;
    if (b < eblocks) {
        row = rowA; col = colA; val = valA; kbase = 0;
    } else {
        row = rowL; col = colL; val = valL; kbase = NBC;
        b -= eblocks;
    }
    int e = b * 256 + threadIdx.x;
    if (e >= E) return;
    int r = row[e];
    int k = (kbase + (r >> 9)) * 8 + xcd;          // coarse bin: 512 rows
    int p = atomicAdd(&cur[k], 1);
    if (p < (k + 1) * SST2)                        // cap = stride (2x mean)
        tmp[p] = make_int2(col[e] | ((r & 511) << 20), __float_as_int(val[e]));
}

// Single block: bucket totals from cursors + exclusive scan over NB2 buckets.
__global__ void scan_fused_kernel(const int* __restrict__ cur,
                                  int* __restrict__ boff, int NB2) {
    __shared__ int sh[1024];
    int t = threadIdx.x;  // 1024
    int b0 = t * 4;
    int v[4];
    int s = 0;
#pragma unroll
    for (int j = 0; j < 4; ++j) {
        int b = b0 + j;
        int c = 0;
        if (b < NB2) {
#pragma unroll
            for (int i = 0; i < 8; ++i) {
                int k = b * 8 + i;
                int f = cur[k] - k * SST2;
                c += min(max(f, 0), SST2);
            }
        }
        v[j] = c;
        s += c;
    }
    sh[t] = s;
    __syncthreads();
    for (int off = 1; off < 1024; off <<= 1) {
        int x = (t >= off) ? sh[t - off] : 0;
        __syncthreads();
        sh[t] += x;
        __syncthreads();
    }
    int run = (t == 0) ? 0 : sh[t - 1];
#pragma unroll
    for (int j = 0; j < 4; ++j) {
        int b = b0 + j;
        if (b < NB2) boff[b] = run;
        run += v[j];
    }
}

// One block per coarse bin: LDS-sort bin edges by row (512 rows), emit
// row_ptr + cv. Reads: 8 x 16KB segments coalesced. Writes: cv within a
// 64KB window (lines fill fully -> ~1x write-amp).
__global__ void place_kernel(const int* __restrict__ cur,
                             const int* __restrict__ boff,
                             const int2* __restrict__ tmp,
                             int* __restrict__ rpA, int* __restrict__ rpL,
                             int2* __restrict__ cvA, int2* __restrict__ cvL,
                             int n, int NBC) {
    int b = blockIdx.x;  // 0..2*NBC-1
    int m = (b >= NBC) ? 1 : 0;
    int lb = b - m * NBC;
    int r0 = lb * RPB;
    int r1 = min(r0 + RPB, n);
    int* rp = m ? rpL : rpA;
    int2* cv = m ? cvL : cvA;
    int lbase = m ? boff[NBC] : 0;          // L's cv/rp offsets are local
    int p0 = boff[b] - lbase;
    __shared__ int cnt[RPB], curs[RPB], rbase[RPB];
    __shared__ int fill[8], fbase[9];
    __shared__ int2 stage[STAGE_CAP];       // 72 KB; total static ~80 KB
    int t = threadIdx.x;
    for (int i = t; i < RPB; i += 256) cnt[i] = 0;
    if (t < 8) {
        int k = b * 8 + t;
        int f = cur[k] - k * SST2;
        fill[t] = min(max(f, 0), SST2);
    }
    __syncthreads();
    if (t == 0) {
        int r = 0;
#pragma unroll
        for (int i = 0; i < 8; ++i) { fbase[i] = r; r += fill[i]; }
        fbase[8] = min(r, STAGE_CAP);
    }
    __syncthreads();
    int total = fbase[8];
    // coalesced per-segment load into stage + LDS row histogram
#pragma unroll
    for (int sg = 0; sg < 8; ++sg) {
        int f = fill[sg];
        const int2* src = tmp + (size_t)(b * 8 + sg) * SST2;
        int fb = fbase[sg];
        for (int i = t; i < f; i += 256) {
            int d = fb + i;
            if (d < STAGE_CAP) {
                int2 e = src[i];
                stage[d] = e;
                atomicAdd(&cnt[(e.x >> 20) & (RPB - 1)], 1);
            }
        }
    }
    __syncthreads();
    // exclusive scan over 512 row counts: wave 0, 8 serial per lane + ladder
    if (t < 64) {
        int base = t * 8;
        int loc[8];
        int s = 0;
#pragma unroll
        for (int j = 0; j < 8; ++j) { loc[j] = s; s += cnt[base + j]; }
        int sc = s;
#pragma unroll
        for (int off = 1; off < 64; off <<= 1) {
            int y = __shfl_up(sc, off, 64);
            if (t >= off) sc += y;
        }
        int ex = sc - s;
#pragma unroll
        for (int j = 0; j < 8; ++j) {
            rbase[base + j] = ex + loc[j];
            curs[base + j] = ex + loc[j];
        }
    }
    __syncthreads();
    for (int rr = t; rr < r1 - r0; rr += 256) rp[r0 + rr] = p0 + rbase[rr];
    if (t == 0 && lb == NBC - 1) rp[n] = p0 + total;  // sentinel
    __syncthreads();
    for (int i = t; i < total; i += 256) {
        int2 e = stage[i];
        int pos = atomicAdd(&curs[(e.x >> 20) & (RPB - 1)], 1);
        cv[p0 + pos] = make_int2(e.x & 0xFFFFF, e.y);
    }
}

// ---------------------------------------------------------------------------
// Fused GNN layer v7: quarter-owns-row (unchanged — near its gather
// L3-BW ceiling: 221 MB L2-miss @ 2.3 TB/s ~= 95 us).
// ---------------------------------------------------------------------------
__global__ void fused_layer_kernel(const int* __restrict__ row_ptr,
                                   const int2* __restrict__ cv,
                                   const float* __restrict__ X,
                                   const float* __restrict__ W,
                                   float* __restrict__ Xn,
                                   float* __restrict__ s,
                                   const float* __restrict__ Wsv, int n) {
    __shared__ float Wt[64 * 68];       // Wt[k*68 + f] = W[f][k]; float4-aligned
    int tid = threadIdx.x;
    for (int i = tid; i < 4096; i += 256) {
        int j = i >> 6, k = i & 63;     // W[j,k] row-major
        Wt[k * 68 + j] = W[i];
    }
    __syncthreads();
    int lane = tid & 63;
    int ql = lane & 15;
    int q = lane >> 4;                  // quarter 0..3 — owns row rbase+q
    int wv = tid >> 6;
    float4 ws4 = {0.f, 0.f, 0.f, 0.f};
    if (s != nullptr) ws4 = *(const float4*)&Wsv[4 * ql];
    int rbase = (blockIdx.x * 4 + wv) * 4;      // exactly one group per wave
    if (rbase >= n) return;
    int row = rbase + q;
    bool act = row < n;
    int rr = act ? row : 0;                     // clamped: loads always valid
    int p0 = row_ptr[rr];
    int end = act ? row_ptr[rr + 1] : p0;
    // ---- gather: quarter walks its own row's edges, 4-deep unroll ----
    float4 a0 = {0.f, 0.f, 0.f, 0.f}, a1 = {0.f, 0.f, 0.f, 0.f};
    float4 a2 = {0.f, 0.f, 0.f, 0.f}, a3 = {0.f, 0.f, 0.f, 0.f};
    int p = p0;
    for (; p + 3 < end; p += 4) {
        int2 e0 = cv[p], e1 = cv[p + 1], e2 = cv[p + 2], e3 = cv[p + 3];
        float4 x0 = *(const float4*)&X[(size_t)e0.x * 64 + 4 * ql];
        float4 x1 = *(const float4*)&X[(size_t)e1.x * 64 + 4 * ql];
        float4 x2 = *(const float4*)&X[(size_t)e2.x * 64 + 4 * ql];
        float4 x3 = *(const float4*)&X[(size_t)e3.x * 64 + 4 * ql];
        float v0 = __int_as_float(e0.y), v1 = __int_as_float(e1.y);
        float v2 = __int_as_float(e2.y), v3 = __int_as_float(e3.y);
        a0.x += v0 * x0.x; a0.y += v0 * x0.y; a0.z += v0 * x0.z; a0.w += v0 * x0.w;
        a1.x += v1 * x1.x; a1.y += v1 * x1.y; a1.z += v1 * x1.z; a1.w += v1 * x1.w;
        a2.x += v2 * x2.x; a2.y += v2 * x2.y; a2.z += v2 * x2.z; a2.w += v2 * x2.w;
        a3.x += v3 * x3.x; a3.y += v3 * x3.y; a3.z += v3 * x3.z; a3.w += v3 * x3.w;
    }
    for (; p < end; ++p) {
        int2 e = cv[p];
        float4 x = *(const float4*)&X[(size_t)e.x * 64 + 4 * ql];
        float v = __int_as_float(e.y);
        a0.x += v * x.x; a0.y += v * x.y; a0.z += v * x.z; a0.w += v * x.w;
    }
    float4 acc;
    acc.x = (a0.x + a1.x) + (a2.x + a3.x);
    acc.y = (a0.y + a1.y) + (a2.y + a3.y);
    acc.z = (a0.z + a1.z) + (a2.z + a3.z);
    acc.w = (a0.w + a1.w) + (a2.w + a3.w);
    // acc is COMPLETE within the quarter: lane ql holds AX[4ql..4ql+4).
    // ---- matvec: full k range; width-64 shfl from quarter-local lane;
    //      Wt reads are q-independent (4-way broadcast, 2-way alias) ----
    float4 h4 = {0.f, 0.f, 0.f, 0.f};
    int qb = 16 * q;
#pragma unroll
    for (int kk = 0; kk < 64; kk += 4) {
        int src = qb + (kk >> 2);               // lane holding acc[kk..kk+4) for this quarter
        float b0 = __shfl(acc.x, src, 64);
        float b1 = __shfl(acc.y, src, 64);
        float b2 = __shfl(acc.z, src, 64);
        float b3 = __shfl(acc.w, src, 64);
        float4 w0 = *(const float4*)&Wt[(kk + 0) * 68 + 4 * ql];
        float4 w1 = *(const float4*)&Wt[(kk + 1) * 68 + 4 * ql];
        float4 w2 = *(const float4*)&Wt[(kk + 2) * 68 + 4 * ql];
        float4 w3 = *(const float4*)&Wt[(kk + 3) * 68 + 4 * ql];
        h4.x += b0 * w0.x + b1 * w1.x + b2 * w2.x + b3 * w3.x;
        h4.y += b0 * w0.y + b1 * w1.y + b2 * w2.y + b3 * w3.y;
        h4.z += b0 * w0.z + b1 * w1.z + b2 * w2.z + b3 * w3.z;
        h4.w += b0 * w0.w + b1 * w1.w + b2 * w2.w + b3 * w3.w;
    }
    // ---- residual + coalesced store + folded score (per quarter) ----
    if (act) {
        float4 xv = *(const float4*)&X[(size_t)row * 64 + 4 * ql];
        float4 o;
        o.x = xv.x + fmaxf(h4.x, 0.f);
        o.y = xv.y + fmaxf(h4.y, 0.f);
        o.z = xv.z + fmaxf(h4.z, 0.f);
        o.w = xv.w + fmaxf(h4.w, 0.f);
        *(float4*)&Xn[(size_t)row * 64 + 4 * ql] = o;
        if (s != nullptr) {
            float d = o.x * ws4.x + o.y * ws4.y + o.z * ws4.z + o.w * ws4.w;
#pragma unroll
            for (int off = 8; off; off >>= 1) d += __shfl_down(d, off, 16);
            if (ql == 0) s[row] = d;
        }
    }
}

// ---------------------------------------------------------------------------
// Fused power iteration v3 (4 lanes/row — proven local opt; 16-lane variant
// cost +24us/iter from per-wave fixed overhead scaling with wave count).
// ---------------------------------------------------------------------------
__global__ void power_iter_kernel(const int* __restrict__ row_ptr,
                                  const int2* __restrict__ cv,
                                  const float* __restrict__ v_in,
                                  float* __restrict__ v_out,
                                  const float* __restrict__ norm_prev,  // 64 slots or null
                                  float* __restrict__ norm_out,         // 64 slots
                                  int n) {
    int lane = threadIdx.x & 63;
    float scale = 1.f;
    if (norm_prev) {
        float x = norm_prev[lane];
#pragma unroll
        for (int off = 32; off; off >>= 1) x += __shfl_xor(x, off, 64);
        scale = 1.f / fmaxf(sqrtf(x), 1e-12f);
    }
    int g = blockIdx.x * 256 + threadIdx.x;
    int row = g >> 2;
    int t = g & 3;
    float sq = 0.f;
    if (row < n) {
        int p = row_ptr[row] + t;
        int end = row_ptr[row + 1];
        float s0 = 0.f, s1 = 0.f, s2 = 0.f, s3 = 0.f;
        for (; p + 12 < end; p += 16) {
            int2 e0 = cv[p], e1 = cv[p + 4], e2 = cv[p + 8], e3 = cv[p + 12];
            s0 += __int_as_float(e0.y) * v_in[e0.x];
            s1 += __int_as_float(e1.y) * v_in[e1.x];
            s2 += __int_as_float(e2.y) * v_in[e2.x];
            s3 += __int_as_float(e3.y) * v_in[e3.x];
        }
        for (; p < end; p += 4) {
            int2 e = cv[p];
            s0 += __int_as_float(e.y) * v_in[e.x];
        }
        float sv = (s0 + s1) + (s2 + s3);
        sv += __shfl_xor(sv, 2, 4);
        sv += __shfl_xor(sv, 1, 4);
        if (t == 0) {
            float sg = (sv > 0.f) ? 1.f : ((sv < 0.f) ? -1.f : 0.f);
            float w = sv * scale - TAU * sg;
            v_out[row] = w;
            sq = w * w;
        }
    }
    for (int off = 32; off; off >>= 1) sq += __shfl_down(sq, off, 64);
    __shared__ float sh[4];
    int wv = threadIdx.x >> 6;
    if (lane == 0) sh[wv] = sq;
    __syncthreads();
    if (threadIdx.x == 0)
        atomicAdd(&norm_out[blockIdx.x & 63], sh[0] + sh[1] + sh[2] + sh[3]);
}

__global__ void finalize_kernel(const float* __restrict__ v,
                                const float* __restrict__ slots,
                                float* __restrict__ out, int n) {
    int lane = threadIdx.x & 63;
    float x = slots[lane];
#pragma unroll
    for (int off = 32; off; off >>= 1) x += __shfl_xor(x, off, 64);
    float inv = 1.f / fmaxf(sqrtf(x), 1e-12f);
    int i = blockIdx.x * 256 + threadIdx.x;
    if (i < n) out[i] = v[i] * inv;
}

extern "C" void kernel_launch(void* const* d_in, const int* in_sizes, int n_in,
                              void* d_out, int out_size, void* d_ws, size_t ws_size,
                              hipStream_t stream) {
    const int* A_row = (const int*)d_in[0];
    const int* A_col = (const int*)d_in[1];
    const float* A_val = (const float*)d_in[2];
    const int* L_row = (const int*)d_in[3];
    const int* L_col = (const int*)d_in[4];
    const float* L_val = (const float*)d_in[5];
    const float* embed = (const float*)d_in[6];
    const float* W1 = (const float*)d_in[7];
    const float* W2 = (const float*)d_in[8];
    const float* Ws = (const float*)d_in[9];
    float* out = (float*)d_out;

    const int E = in_sizes[0];
    const int D = 64;
    const int N = in_sizes[6] / D;
    const int ITERS = 10;
    const int NBC = (N + RPB - 1) / RPB;  // coarse bins per matrix (196)
    const int NBC2 = 2 * NBC;
    const int K2 = NBC2 * 8;              // segment cursors (3136)

    char* ws = (char*)d_ws;
    size_t off = 0;
    auto carve = [&](size_t bytes) {
        void* p = ws + off;
        off += (bytes + 255) & ~(size_t)255;
        return p;
    };
    size_t feat_bytes = (size_t)N * D * sizeof(float);
    size_t tmp_bytes = (size_t)K2 * SST2 * sizeof(int2);   // 51.4 MB
    // X0/X1 and tmp share one region (tmp dead once place ran; X live after)
    char* base = (char*)carve(tmp_bytes > 2 * feat_bytes ? tmp_bytes : 2 * feat_bytes);
    float* X0 = (float*)base;
    float* X1 = (float*)(base + feat_bytes);
    int2* tmp = (int2*)base;
    int* A_rp = (int*)carve((size_t)(N + 1) * sizeof(int));
    int2* A_cv = (int2*)carve((size_t)E * sizeof(int2));
    int* L_rp = (int*)carve((size_t)(N + 1) * sizeof(int));
    int2* L_cv = (int2*)carve((size_t)E * sizeof(int2));
    int* cur = (int*)carve((size_t)K2 * sizeof(int));
    int* boff = (int*)carve((size_t)NBC2 * sizeof(int));
    float* v_cur = (float*)carve((size_t)N * sizeof(float));
    float* v_new = (float*)carve((size_t)N * sizeof(float));
    float* norms = (float*)carve((size_t)ITERS * 64 * sizeof(float));

    int e_blocks = (E + 255) / 256;

    // ---- CSR build: coarse XCD-local binning + 512-row LDS sort ----
    init_kernel<<<(K2 + 255) / 256, 256, 0, stream>>>(cur, norms, K2, ITERS * 64);
    bin2_kernel<<<2 * e_blocks, 256, 0, stream>>>(A_row, A_col, A_val,
                                                  L_row, L_col, L_val,
                                                  cur, tmp, E, e_blocks, NBC);
    scan_fused_kernel<<<1, 1024, 0, stream>>>(cur, boff, NBC2);
    place_kernel<<<NBC2, 256, 0, stream>>>(cur, boff, tmp,
                                           A_rp, L_rp, A_cv, L_cv, N, NBC);

    // ---- two fused residual GNN layers (layer 2 also emits scores) ----
    // one 4-row group per wave: (N+15)/16 blocks of 4 waves
    int fl_blocks = (N + 15) / 16;
    fused_layer_kernel<<<fl_blocks, 256, 0, stream>>>(
        A_rp, A_cv, embed, W1, X0, nullptr, Ws, N);
    fused_layer_kernel<<<fl_blocks, 256, 0, stream>>>(
        A_rp, A_cv, X0, W2, X1, v_cur, Ws, N);

    // ---- power iterations (normalize folded; 64-slot norm partials) ----
    int p_blocks = (N * 4 + 255) / 256;
    int n_blocks = (N + 255) / 256;
    float* cur_v = v_cur;
    float* nxt_v = v_new;
    for (int it = 0; it < ITERS; ++it) {
        power_iter_kernel<<<p_blocks, 256, 0, stream>>>(
            L_rp, L_cv, cur_v, nxt_v,
            it ? (norms + (it - 1) * 64) : nullptr, norms + it * 64, N);
        float* t = cur_v; cur_v = nxt_v; nxt_v = t;
    }
    finalize_kernel<<<n_blocks, 256, 0, stream>>>(cur_v, norms + (ITERS - 1) * 64, out, N);
}

// Round 7
// 554.508 us; speedup vs baseline: 1.8106x; 1.8106x over previous
//
#include <hip/hip_runtime.h>
#include <hip/hip_bf16.h>
#include <math.h>

#define TAU 0.5f
#define RPB 256        // rows per bucket (place sort range)
#define SEG 4608       // segment stride/cap (entries): mean fill 4082, +8 sigma
#define CHUNK 8192     // edges per bin block chunk

// ---------------------------------------------------------------------------
// CSR build v5: block-aggregated counting sort.
//   R6 lessons: per-edge random 8B stores carry ~5x write-amp REGARDLESS of
//   segment count (fine 136MB / coarse 127MB WRITE_SIZE), and per-edge global
//   atomics serialize (coarse: 3x slower at same traffic, VALU 0.3%).
//   v5: per-edge atomics -> LDS; ONE global atomic per block x bucket (~150K
//   total, 20x fewer); writes become ~21-entry (168B) contiguous runs per
//   bucket per block -> lines fill -> write-amp ~1.3x.
// ---------------------------------------------------------------------------
__global__ void init_kernel(int* __restrict__ cur, float* __restrict__ norms,
                            int K, int NN) {
    int k = blockIdx.x * 256 + threadIdx.x;
    if (k < K) cur[k] = 0;
    if (k < NN) norms[k] = 0.f;
}

__global__ __launch_bounds__(512)
void bin3_kernel(const int* __restrict__ rowA, const int* __restrict__ colA,
                 const float* __restrict__ valA,
                 const int* __restrict__ rowL, const int* __restrict__ colL,
                 const float* __restrict__ valL,
                 int* __restrict__ cur, int2* __restrict__ tmp,
                 int E, int cblocks, int NBC) {
    __shared__ int cnt[512];
    __shared__ int sbase[512];
    int b = blockIdx.x;
    const int* row;
    const int* col;
    const float* val;
    int koff;
    if (b < cblocks) {
        row = rowA; col = colA; val = valA; koff = 0;
    } else {
        row = rowL; col = colL; val = valL; koff = NBC;
        b -= cblocks;
    }
    int t = threadIdx.x;
    for (int i = t; i < 512; i += 512) cnt[i] = 0;
    __syncthreads();
    int e0 = b * CHUNK;
    int e1 = min(e0 + CHUNK, E);
    // pass 1: LDS histogram over coarse buckets (256 rows each)
    for (int e = e0 + t; e < e1; e += 512)
        atomicAdd(&cnt[row[e] >> 8], 1);
    __syncthreads();
    // one global atomic per non-empty bucket reserves a contiguous run
    if (t < NBC) {
        int c = cnt[t];
        sbase[t] = c ? atomicAdd(&cur[koff + t], c) : 0;
    }
    __syncthreads();
    for (int i = t; i < 512; i += 512) cnt[i] = 0;
    __syncthreads();
    // pass 2: LDS rank + contiguous run write (chunk is L2-hot)
    for (int e = e0 + t; e < e1; e += 512) {
        int r = row[e];
        int bk = r >> 8;
        int rank = atomicAdd(&cnt[bk], 1);
        int pos = sbase[bk] + rank;
        if (pos < SEG)  // +8 sigma cap; clamp prevents OOB
            tmp[(size_t)(koff + bk) * SEG + pos] =
                make_int2(col[e] | ((r & 255) << 20), __float_as_int(val[e]));
    }
}

// Single block: exclusive scan of bucket totals (NB2 <= 1024).
__global__ __launch_bounds__(1024)
void scan_kernel(const int* __restrict__ cur, int* __restrict__ boff, int NB2) {
    __shared__ int sh[1024];
    int t = threadIdx.x;
    int c = (t < NB2) ? min(cur[t], SEG) : 0;
    sh[t] = c;
    __syncthreads();
    for (int off = 1; off < 1024; off <<= 1) {
        int x = (t >= off) ? sh[t - off] : 0;
        __syncthreads();
        sh[t] += x;
        __syncthreads();
    }
    if (t < NB2) boff[t] = sh[t] - c;   // exclusive prefix
}

// One block per bucket: LDS-sort bucket edges by row (256 rows), emit
// row_ptr + cv. Reads one contiguous segment; cv writes window-local.
__global__ __launch_bounds__(256)
void place_kernel(const int* __restrict__ cur,
                  const int* __restrict__ boff,
                  const int2* __restrict__ tmp,
                  int* __restrict__ rpA, int* __restrict__ rpL,
                  int2* __restrict__ cvA, int2* __restrict__ cvL,
                  int n, int NBC) {
    int b = blockIdx.x;  // 0..2*NBC-1
    int m = (b >= NBC) ? 1 : 0;
    int lb = b - m * NBC;
    int r0 = lb * RPB;
    int r1 = min(r0 + RPB, n);
    int* rp = m ? rpL : rpA;
    int2* cv = m ? cvL : cvA;
    int lbase = m ? boff[NBC] : 0;          // L's cv/rp offsets are local
    int p0 = boff[b] - lbase;
    __shared__ int cnt[RPB], curs[RPB], rbase[RPB];
    __shared__ int2 stage[SEG];             // 36 KB
    int t = threadIdx.x;                    // 256
    if (t < RPB) cnt[t] = 0;
    __syncthreads();
    int fill = min(cur[b], SEG);
    const int2* src = tmp + (size_t)b * SEG;
    for (int i = t; i < fill; i += 256) {
        int2 e = src[i];
        stage[i] = e;
        atomicAdd(&cnt[(e.x >> 20) & (RPB - 1)], 1);
    }
    __syncthreads();
    // exclusive scan over 256 row counts: wave 0, 4 serial per lane + ladder
    if (t < 64) {
        int base = t * 4;
        int loc[4];
        int s = 0;
#pragma unroll
        for (int j = 0; j < 4; ++j) { loc[j] = s; s += cnt[base + j]; }
        int sc = s;
#pragma unroll
        for (int off = 1; off < 64; off <<= 1) {
            int y = __shfl_up(sc, off, 64);
            if (t >= off) sc += y;
        }
        int ex = sc - s;
#pragma unroll
        for (int j = 0; j < 4; ++j) {
            rbase[base + j] = ex + loc[j];
            curs[base + j] = ex + loc[j];
        }
    }
    __syncthreads();
    if (t < r1 - r0) rp[r0 + t] = p0 + rbase[t];
    if (t == 0 && lb == NBC - 1) rp[n] = p0 + fill;  // sentinel
    __syncthreads();
    for (int i = t; i < fill; i += 256) {
        int2 e = stage[i];
        int pos = atomicAdd(&curs[(e.x >> 20) & (RPB - 1)], 1);
        cv[p0 + pos] = make_int2(e.x & 0xFFFFF, e.y);
    }
}

// ---------------------------------------------------------------------------
// Fused GNN layer v7: quarter-owns-row (unchanged — near its gather
// L3-BW ceiling: 221 MB L2-miss @ 2.3 TB/s ~= 95 us).
// ---------------------------------------------------------------------------
__global__ void fused_layer_kernel(const int* __restrict__ row_ptr,
                                   const int2* __restrict__ cv,
                                   const float* __restrict__ X,
                                   const float* __restrict__ W,
                                   float* __restrict__ Xn,
                                   float* __restrict__ s,
                                   const float* __restrict__ Wsv, int n) {
    __shared__ float Wt[64 * 68];       // Wt[k*68 + f] = W[f][k]; float4-aligned
    int tid = threadIdx.x;
    for (int i = tid; i < 4096; i += 256) {
        int j = i >> 6, k = i & 63;     // W[j,k] row-major
        Wt[k * 68 + j] = W[i];
    }
    __syncthreads();
    int lane = tid & 63;
    int ql = lane & 15;
    int q = lane >> 4;                  // quarter 0..3 — owns row rbase+q
    int wv = tid >> 6;
    float4 ws4 = {0.f, 0.f, 0.f, 0.f};
    if (s != nullptr) ws4 = *(const float4*)&Wsv[4 * ql];
    int rbase = (blockIdx.x * 4 + wv) * 4;      // exactly one group per wave
    if (rbase >= n) return;
    int row = rbase + q;
    bool act = row < n;
    int rr = act ? row : 0;                     // clamped: loads always valid
    int p0 = row_ptr[rr];
    int end = act ? row_ptr[rr + 1] : p0;
    // ---- gather: quarter walks its own row's edges, 4-deep unroll ----
    float4 a0 = {0.f, 0.f, 0.f, 0.f}, a1 = {0.f, 0.f, 0.f, 0.f};
    float4 a2 = {0.f, 0.f, 0.f, 0.f}, a3 = {0.f, 0.f, 0.f, 0.f};
    int p = p0;
    for (; p + 3 < end; p += 4) {
        int2 e0 = cv[p], e1 = cv[p + 1], e2 = cv[p + 2], e3 = cv[p + 3];
        float4 x0 = *(const float4*)&X[(size_t)e0.x * 64 + 4 * ql];
        float4 x1 = *(const float4*)&X[(size_t)e1.x * 64 + 4 * ql];
        float4 x2 = *(const float4*)&X[(size_t)e2.x * 64 + 4 * ql];
        float4 x3 = *(const float4*)&X[(size_t)e3.x * 64 + 4 * ql];
        float v0 = __int_as_float(e0.y), v1 = __int_as_float(e1.y);
        float v2 = __int_as_float(e2.y), v3 = __int_as_float(e3.y);
        a0.x += v0 * x0.x; a0.y += v0 * x0.y; a0.z += v0 * x0.z; a0.w += v0 * x0.w;
        a1.x += v1 * x1.x; a1.y += v1 * x1.y; a1.z += v1 * x1.z; a1.w += v1 * x1.w;
        a2.x += v2 * x2.x; a2.y += v2 * x2.y; a2.z += v2 * x2.z; a2.w += v2 * x2.w;
        a3.x += v3 * x3.x; a3.y += v3 * x3.y; a3.z += v3 * x3.z; a3.w += v3 * x3.w;
    }
    for (; p < end; ++p) {
        int2 e = cv[p];
        float4 x = *(const float4*)&X[(size_t)e.x * 64 + 4 * ql];
        float v = __int_as_float(e.y);
        a0.x += v * x.x; a0.y += v * x.y; a0.z += v * x.z; a0.w += v * x.w;
    }
    float4 acc;
    acc.x = (a0.x + a1.x) + (a2.x + a3.x);
    acc.y = (a0.y + a1.y) + (a2.y + a3.y);
    acc.z = (a0.z + a1.z) + (a2.z + a3.z);
    acc.w = (a0.w + a1.w) + (a2.w + a3.w);
    // acc is COMPLETE within the quarter: lane ql holds AX[4ql..4ql+4).
    // ---- matvec: full k range; width-64 shfl from quarter-local lane;
    //      Wt reads are q-independent (4-way broadcast, 2-way alias) ----
    float4 h4 = {0.f, 0.f, 0.f, 0.f};
    int qb = 16 * q;
#pragma unroll
    for (int kk = 0; kk < 64; kk += 4) {
        int src = qb + (kk >> 2);               // lane holding acc[kk..kk+4) for this quarter
        float b0 = __shfl(acc.x, src, 64);
        float b1 = __shfl(acc.y, src, 64);
        float b2 = __shfl(acc.z, src, 64);
        float b3 = __shfl(acc.w, src, 64);
        float4 w0 = *(const float4*)&Wt[(kk + 0) * 68 + 4 * ql];
        float4 w1 = *(const float4*)&Wt[(kk + 1) * 68 + 4 * ql];
        float4 w2 = *(const float4*)&Wt[(kk + 2) * 68 + 4 * ql];
        float4 w3 = *(const float4*)&Wt[(kk + 3) * 68 + 4 * ql];
        h4.x += b0 * w0.x + b1 * w1.x + b2 * w2.x + b3 * w3.x;
        h4.y += b0 * w0.y + b1 * w1.y + b2 * w2.y + b3 * w3.y;
        h4.z += b0 * w0.z + b1 * w1.z + b2 * w2.z + b3 * w3.z;
        h4.w += b0 * w0.w + b1 * w1.w + b2 * w2.w + b3 * w3.w;
    }
    // ---- residual + coalesced store + folded score (per quarter) ----
    if (act) {
        float4 xv = *(const float4*)&X[(size_t)row * 64 + 4 * ql];
        float4 o;
        o.x = xv.x + fmaxf(h4.x, 0.f);
        o.y = xv.y + fmaxf(h4.y, 0.f);
        o.z = xv.z + fmaxf(h4.z, 0.f);
        o.w = xv.w + fmaxf(h4.w, 0.f);
        *(float4*)&Xn[(size_t)row * 64 + 4 * ql] = o;
        if (s != nullptr) {
            float d = o.x * ws4.x + o.y * ws4.y + o.z * ws4.z + o.w * ws4.w;
#pragma unroll
            for (int off = 8; off; off >>= 1) d += __shfl_down(d, off, 16);
            if (ql == 0) s[row] = d;
        }
    }
}

// ---------------------------------------------------------------------------
// Fused power iteration v3 (4 lanes/row — proven local opt; 16-lane variant
// cost +24us/iter from per-wave fixed overhead scaling with wave count).
// ---------------------------------------------------------------------------
__global__ void power_iter_kernel(const int* __restrict__ row_ptr,
                                  const int2* __restrict__ cv,
                                  const float* __restrict__ v_in,
                                  float* __restrict__ v_out,
                                  const float* __restrict__ norm_prev,  // 64 slots or null
                                  float* __restrict__ norm_out,         // 64 slots
                                  int n) {
    int lane = threadIdx.x & 63;
    float scale = 1.f;
    if (norm_prev) {
        float x = norm_prev[lane];
#pragma unroll
        for (int off = 32; off; off >>= 1) x += __shfl_xor(x, off, 64);
        scale = 1.f / fmaxf(sqrtf(x), 1e-12f);
    }
    int g = blockIdx.x * 256 + threadIdx.x;
    int row = g >> 2;
    int t = g & 3;
    float sq = 0.f;
    if (row < n) {
        int p = row_ptr[row] + t;
        int end = row_ptr[row + 1];
        float s0 = 0.f, s1 = 0.f, s2 = 0.f, s3 = 0.f;
        for (; p + 12 < end; p += 16) {
            int2 e0 = cv[p], e1 = cv[p + 4], e2 = cv[p + 8], e3 = cv[p + 12];
            s0 += __int_as_float(e0.y) * v_in[e0.x];
            s1 += __int_as_float(e1.y) * v_in[e1.x];
            s2 += __int_as_float(e2.y) * v_in[e2.x];
            s3 += __int_as_float(e3.y) * v_in[e3.x];
        }
        for (; p < end; p += 4) {
            int2 e = cv[p];
            s0 += __int_as_float(e.y) * v_in[e.x];
        }
        float sv = (s0 + s1) + (s2 + s3);
        sv += __shfl_xor(sv, 2, 4);
        sv += __shfl_xor(sv, 1, 4);
        if (t == 0) {
            float sg = (sv > 0.f) ? 1.f : ((sv < 0.f) ? -1.f : 0.f);
            float w = sv * scale - TAU * sg;
            v_out[row] = w;
            sq = w * w;
        }
    }
    for (int off = 32; off; off >>= 1) sq += __shfl_down(sq, off, 64);
    __shared__ float sh[4];
    int wv = threadIdx.x >> 6;
    if (lane == 0) sh[wv] = sq;
    __syncthreads();
    if (threadIdx.x == 0)
        atomicAdd(&norm_out[blockIdx.x & 63], sh[0] + sh[1] + sh[2] + sh[3]);
}

__global__ void finalize_kernel(const float* __restrict__ v,
                                const float* __restrict__ slots,
                                float* __restrict__ out, int n) {
    int lane = threadIdx.x & 63;
    float x = slots[lane];
#pragma unroll
    for (int off = 32; off; off >>= 1) x += __shfl_xor(x, off, 64);
    float inv = 1.f / fmaxf(sqrtf(x), 1e-12f);
    int i = blockIdx.x * 256 + threadIdx.x;
    if (i < n) out[i] = v[i] * inv;
}

extern "C" void kernel_launch(void* const* d_in, const int* in_sizes, int n_in,
                              void* d_out, int out_size, void* d_ws, size_t ws_size,
                              hipStream_t stream) {
    const int* A_row = (const int*)d_in[0];
    const int* A_col = (const int*)d_in[1];
    const float* A_val = (const float*)d_in[2];
    const int* L_row = (const int*)d_in[3];
    const int* L_col = (const int*)d_in[4];
    const float* L_val = (const float*)d_in[5];
    const float* embed = (const float*)d_in[6];
    const float* W1 = (const float*)d_in[7];
    const float* W2 = (const float*)d_in[8];
    const float* Ws = (const float*)d_in[9];
    float* out = (float*)d_out;

    const int E = in_sizes[0];
    const int D = 64;
    const int N = in_sizes[6] / D;
    const int ITERS = 10;
    const int NBC = (N + RPB - 1) / RPB;  // buckets per matrix (391)
    const int NB2 = 2 * NBC;              // 782
    const int cblocks = (E + CHUNK - 1) / CHUNK;  // bin blocks per matrix (196)

    char* ws = (char*)d_ws;
    size_t off = 0;
    auto carve = [&](size_t bytes) {
        void* p = ws + off;
        off += (bytes + 255) & ~(size_t)255;
        return p;
    };
    size_t feat_bytes = (size_t)N * D * sizeof(float);
    size_t tmp_bytes = (size_t)NB2 * SEG * sizeof(int2);   // 28.8 MB
    // X0/X1 and tmp share one region (tmp dead once place ran; X live after)
    char* base = (char*)carve(tmp_bytes > 2 * feat_bytes ? tmp_bytes : 2 * feat_bytes);
    float* X0 = (float*)base;
    float* X1 = (float*)(base + feat_bytes);
    int2* tmp = (int2*)base;
    int* A_rp = (int*)carve((size_t)(N + 1) * sizeof(int));
    int2* A_cv = (int2*)carve((size_t)E * sizeof(int2));
    int* L_rp = (int*)carve((size_t)(N + 1) * sizeof(int));
    int2* L_cv = (int2*)carve((size_t)E * sizeof(int2));
    int* cur = (int*)carve((size_t)NB2 * sizeof(int));
    int* boff = (int*)carve((size_t)NB2 * sizeof(int));
    float* v_cur = (float*)carve((size_t)N * sizeof(float));
    float* v_new = (float*)carve((size_t)N * sizeof(float));
    float* norms = (float*)carve((size_t)ITERS * 64 * sizeof(float));

    // ---- CSR build: block-aggregated counting sort ----
    int imax = NB2 > ITERS * 64 ? NB2 : ITERS * 64;
    init_kernel<<<(imax + 255) / 256, 256, 0, stream>>>(cur, norms, NB2, ITERS * 64);
    bin3_kernel<<<2 * cblocks, 512, 0, stream>>>(A_row, A_col, A_val,
                                                 L_row, L_col, L_val,
                                                 cur, tmp, E, cblocks, NBC);
    scan_kernel<<<1, 1024, 0, stream>>>(cur, boff, NB2);
    place_kernel<<<NB2, 256, 0, stream>>>(cur, boff, tmp,
                                          A_rp, L_rp, A_cv, L_cv, N, NBC);

    // ---- two fused residual GNN layers (layer 2 also emits scores) ----
    // one 4-row group per wave: (N+15)/16 blocks of 4 waves
    int fl_blocks = (N + 15) / 16;
    fused_layer_kernel<<<fl_blocks, 256, 0, stream>>>(
        A_rp, A_cv, embed, W1, X0, nullptr, Ws, N);
    fused_layer_kernel<<<fl_blocks, 256, 0, stream>>>(
        A_rp, A_cv, X0, W2, X1, v_cur, Ws, N);

    // ---- power iterations (normalize folded; 64-slot norm partials) ----
    int p_blocks = (N * 4 + 255) / 256;
    int n_blocks = (N + 255) / 256;
    float* cur_v = v_cur;
    float* nxt_v = v_new;
    for (int it = 0; it < ITERS; ++it) {
        power_iter_kernel<<<p_blocks, 256, 0, stream>>>(
            L_rp, L_cv, cur_v, nxt_v,
            it ? (norms + (it - 1) * 64) : nullptr, norms + it * 64, N);
        float* t = cur_v; cur_v = nxt_v; nxt_v = t;
    }
    finalize_kernel<<<n_blocks, 256, 0, stream>>>(cur_v, norms + (ITERS - 1) * 64, out, N);
}

// Round 8
// 522.698 us; speedup vs baseline: 1.9208x; 1.0609x over previous
//
#include <hip/hip_runtime.h>
#include <hip/hip_bf16.h>
#include <math.h>

#define TAU 0.5f
#define RPB 256        // rows per bucket (place sort range)
#define SEG 4608       // segment stride/cap (entries): mean fill 4082, +8 sigma
#define CHUNK 8192     // edges per bin block chunk

// ---------------------------------------------------------------------------
// CSR build v5: block-aggregated counting sort (R7: bin left top-5; 163->~40us).
//   Per-edge atomics -> LDS; ONE global atomic per block x bucket; writes are
//   ~21-entry contiguous runs -> write-amp ~1.3x (vs 5x for random 8B scatter).
// ---------------------------------------------------------------------------
__global__ void init_kernel(int* __restrict__ cur, float* __restrict__ norms,
                            int K, int NN) {
    int k = blockIdx.x * 256 + threadIdx.x;
    if (k < K) cur[k] = 0;
    if (k < NN) norms[k] = 0.f;
}

__global__ __launch_bounds__(512)
void bin3_kernel(const int* __restrict__ rowA, const int* __restrict__ colA,
                 const float* __restrict__ valA,
                 const int* __restrict__ rowL, const int* __restrict__ colL,
                 const float* __restrict__ valL,
                 int* __restrict__ cur, int2* __restrict__ tmp,
                 int E, int cblocks, int NBC) {
    __shared__ int cnt[512];
    __shared__ int sbase[512];
    int b = blockIdx.x;
    const int* row;
    const int* col;
    const float* val;
    int koff;
    if (b < cblocks) {
        row = rowA; col = colA; val = valA; koff = 0;
    } else {
        row = rowL; col = colL; val = valL; koff = NBC;
        b -= cblocks;
    }
    int t = threadIdx.x;
    for (int i = t; i < 512; i += 512) cnt[i] = 0;
    __syncthreads();
    int e0 = b * CHUNK;
    int e1 = min(e0 + CHUNK, E);
    // pass 1: LDS histogram over coarse buckets (256 rows each)
    for (int e = e0 + t; e < e1; e += 512)
        atomicAdd(&cnt[row[e] >> 8], 1);
    __syncthreads();
    // one global atomic per non-empty bucket reserves a contiguous run
    if (t < NBC) {
        int c = cnt[t];
        sbase[t] = c ? atomicAdd(&cur[koff + t], c) : 0;
    }
    __syncthreads();
    for (int i = t; i < 512; i += 512) cnt[i] = 0;
    __syncthreads();
    // pass 2: LDS rank + contiguous run write (chunk is L2-hot)
    for (int e = e0 + t; e < e1; e += 512) {
        int r = row[e];
        int bk = r >> 8;
        int rank = atomicAdd(&cnt[bk], 1);
        int pos = sbase[bk] + rank;
        if (pos < SEG)  // +8 sigma cap; clamp prevents OOB
            tmp[(size_t)(koff + bk) * SEG + pos] =
                make_int2(col[e] | ((r & 255) << 20), __float_as_int(val[e]));
    }
}

// Single block: exclusive scan of bucket totals (NB2 <= 1024).
__global__ __launch_bounds__(1024)
void scan_kernel(const int* __restrict__ cur, int* __restrict__ boff, int NB2) {
    __shared__ int sh[1024];
    int t = threadIdx.x;
    int c = (t < NB2) ? min(cur[t], SEG) : 0;
    sh[t] = c;
    __syncthreads();
    for (int off = 1; off < 1024; off <<= 1) {
        int x = (t >= off) ? sh[t - off] : 0;
        __syncthreads();
        sh[t] += x;
        __syncthreads();
    }
    if (t < NB2) boff[t] = sh[t] - c;   // exclusive prefix
}

// One block per bucket: LDS-sort bucket edges by row (256 rows), emit
// row_ptr + cv. Reads one contiguous segment; cv writes window-local.
__global__ __launch_bounds__(256)
void place_kernel(const int* __restrict__ cur,
                  const int* __restrict__ boff,
                  const int2* __restrict__ tmp,
                  int* __restrict__ rpA, int* __restrict__ rpL,
                  int2* __restrict__ cvA, int2* __restrict__ cvL,
                  int n, int NBC) {
    int b = blockIdx.x;  // 0..2*NBC-1
    int m = (b >= NBC) ? 1 : 0;
    int lb = b - m * NBC;
    int r0 = lb * RPB;
    int r1 = min(r0 + RPB, n);
    int* rp = m ? rpL : rpA;
    int2* cv = m ? cvL : cvA;
    int lbase = m ? boff[NBC] : 0;          // L's cv/rp offsets are local
    int p0 = boff[b] - lbase;
    __shared__ int cnt[RPB], curs[RPB], rbase[RPB];
    __shared__ int2 stage[SEG];             // 36 KB
    int t = threadIdx.x;                    // 256
    if (t < RPB) cnt[t] = 0;
    __syncthreads();
    int fill = min(cur[b], SEG);
    const int2* src = tmp + (size_t)b * SEG;
    for (int i = t; i < fill; i += 256) {
        int2 e = src[i];
        stage[i] = e;
        atomicAdd(&cnt[(e.x >> 20) & (RPB - 1)], 1);
    }
    __syncthreads();
    // exclusive scan over 256 row counts: wave 0, 4 serial per lane + ladder
    if (t < 64) {
        int base = t * 4;
        int loc[4];
        int s = 0;
#pragma unroll
        for (int j = 0; j < 4; ++j) { loc[j] = s; s += cnt[base + j]; }
        int sc = s;
#pragma unroll
        for (int off = 1; off < 64; off <<= 1) {
            int y = __shfl_up(sc, off, 64);
            if (t >= off) sc += y;
        }
        int ex = sc - s;
#pragma unroll
        for (int j = 0; j < 4; ++j) {
            rbase[base + j] = ex + loc[j];
            curs[base + j] = ex + loc[j];
        }
    }
    __syncthreads();
    if (t < r1 - r0) rp[r0 + t] = p0 + rbase[t];
    if (t == 0 && lb == NBC - 1) rp[n] = p0 + fill;  // sentinel
    __syncthreads();
    for (int i = t; i < fill; i += 256) {
        int2 e = stage[i];
        int pos = atomicAdd(&curs[(e.x >> 20) & (RPB - 1)], 1);
        cv[p0 + pos] = make_int2(e.x & 0xFFFFF, e.y);
    }
}

// ---------------------------------------------------------------------------
// Fused GNN layer v7: quarter-owns-row (unchanged — near its gather
// L3-BW ceiling: 221 MB L2-miss @ 2.3 TB/s ~= 95 us).
// ---------------------------------------------------------------------------
__global__ void fused_layer_kernel(const int* __restrict__ row_ptr,
                                   const int2* __restrict__ cv,
                                   const float* __restrict__ X,
                                   const float* __restrict__ W,
                                   float* __restrict__ Xn,
                                   float* __restrict__ s,
                                   const float* __restrict__ Wsv, int n) {
    __shared__ float Wt[64 * 68];       // Wt[k*68 + f] = W[f][k]; float4-aligned
    int tid = threadIdx.x;
    for (int i = tid; i < 4096; i += 256) {
        int j = i >> 6, k = i & 63;     // W[j,k] row-major
        Wt[k * 68 + j] = W[i];
    }
    __syncthreads();
    int lane = tid & 63;
    int ql = lane & 15;
    int q = lane >> 4;                  // quarter 0..3 — owns row rbase+q
    int wv = tid >> 6;
    float4 ws4 = {0.f, 0.f, 0.f, 0.f};
    if (s != nullptr) ws4 = *(const float4*)&Wsv[4 * ql];
    int rbase = (blockIdx.x * 4 + wv) * 4;      // exactly one group per wave
    if (rbase >= n) return;
    int row = rbase + q;
    bool act = row < n;
    int rr = act ? row : 0;                     // clamped: loads always valid
    int p0 = row_ptr[rr];
    int end = act ? row_ptr[rr + 1] : p0;
    // ---- gather: quarter walks its own row's edges, 4-deep unroll ----
    float4 a0 = {0.f, 0.f, 0.f, 0.f}, a1 = {0.f, 0.f, 0.f, 0.f};
    float4 a2 = {0.f, 0.f, 0.f, 0.f}, a3 = {0.f, 0.f, 0.f, 0.f};
    int p = p0;
    for (; p + 3 < end; p += 4) {
        int2 e0 = cv[p], e1 = cv[p + 1], e2 = cv[p + 2], e3 = cv[p + 3];
        float4 x0 = *(const float4*)&X[(size_t)e0.x * 64 + 4 * ql];
        float4 x1 = *(const float4*)&X[(size_t)e1.x * 64 + 4 * ql];
        float4 x2 = *(const float4*)&X[(size_t)e2.x * 64 + 4 * ql];
        float4 x3 = *(const float4*)&X[(size_t)e3.x * 64 + 4 * ql];
        float v0 = __int_as_float(e0.y), v1 = __int_as_float(e1.y);
        float v2 = __int_as_float(e2.y), v3 = __int_as_float(e3.y);
        a0.x += v0 * x0.x; a0.y += v0 * x0.y; a0.z += v0 * x0.z; a0.w += v0 * x0.w;
        a1.x += v1 * x1.x; a1.y += v1 * x1.y; a1.z += v1 * x1.z; a1.w += v1 * x1.w;
        a2.x += v2 * x2.x; a2.y += v2 * x2.y; a2.z += v2 * x2.z; a2.w += v2 * x2.w;
        a3.x += v3 * x3.x; a3.y += v3 * x3.y; a3.z += v3 * x3.z; a3.w += v3 * x3.w;
    }
    for (; p < end; ++p) {
        int2 e = cv[p];
        float4 x = *(const float4*)&X[(size_t)e.x * 64 + 4 * ql];
        float v = __int_as_float(e.y);
        a0.x += v * x.x; a0.y += v * x.y; a0.z += v * x.z; a0.w += v * x.w;
    }
    float4 acc;
    acc.x = (a0.x + a1.x) + (a2.x + a3.x);
    acc.y = (a0.y + a1.y) + (a2.y + a3.y);
    acc.z = (a0.z + a1.z) + (a2.z + a3.z);
    acc.w = (a0.w + a1.w) + (a2.w + a3.w);
    // acc is COMPLETE within the quarter: lane ql holds AX[4ql..4ql+4).
    // ---- matvec: full k range; width-64 shfl from quarter-local lane;
    //      Wt reads are q-independent (4-way broadcast, 2-way alias) ----
    float4 h4 = {0.f, 0.f, 0.f, 0.f};
    int qb = 16 * q;
#pragma unroll
    for (int kk = 0; kk < 64; kk += 4) {
        int src = qb + (kk >> 2);               // lane holding acc[kk..kk+4) for this quarter
        float b0 = __shfl(acc.x, src, 64);
        float b1 = __shfl(acc.y, src, 64);
        float b2 = __shfl(acc.z, src, 64);
        float b3 = __shfl(acc.w, src, 64);
        float4 w0 = *(const float4*)&Wt[(kk + 0) * 68 + 4 * ql];
        float4 w1 = *(const float4*)&Wt[(kk + 1) * 68 + 4 * ql];
        float4 w2 = *(const float4*)&Wt[(kk + 2) * 68 + 4 * ql];
        float4 w3 = *(const float4*)&Wt[(kk + 3) * 68 + 4 * ql];
        h4.x += b0 * w0.x + b1 * w1.x + b2 * w2.x + b3 * w3.x;
        h4.y += b0 * w0.y + b1 * w1.y + b2 * w2.y + b3 * w3.y;
        h4.z += b0 * w0.z + b1 * w1.z + b2 * w2.z + b3 * w3.z;
        h4.w += b0 * w0.w + b1 * w1.w + b2 * w2.w + b3 * w3.w;
    }
    // ---- residual + coalesced store + folded score (per quarter) ----
    if (act) {
        float4 xv = *(const float4*)&X[(size_t)row * 64 + 4 * ql];
        float4 o;
        o.x = xv.x + fmaxf(h4.x, 0.f);
        o.y = xv.y + fmaxf(h4.y, 0.f);
        o.z = xv.z + fmaxf(h4.z, 0.f);
        o.w = xv.w + fmaxf(h4.w, 0.f);
        *(float4*)&Xn[(size_t)row * 64 + 4 * ql] = o;
        if (s != nullptr) {
            float d = o.x * ws4.x + o.y * ws4.y + o.z * ws4.z + o.w * ws4.w;
#pragma unroll
            for (int off = 8; off; off >>= 1) d += __shfl_down(d, off, 16);
            if (ql == 0) s[row] = d;
        }
    }
}

// ---------------------------------------------------------------------------
// Fused power iteration v5: 2 lanes/row (R4 probe: +18750 waves cost
// +24.3us/iter => ~800cy fixed cost PER WAVE [preamble chain + epilogue
// reduce + sched slot]; halving waves 6252->3128 should cut ~4-5us/iter).
// Per lane: 8 edges as 4 independent 2-deep chains; lanes t={0,1} read
// cv[p0+t] -> pair-contiguous 16B per row per load instruction.
// ---------------------------------------------------------------------------
__global__ void power_iter_kernel(const int* __restrict__ row_ptr,
                                  const int2* __restrict__ cv,
                                  const float* __restrict__ v_in,
                                  float* __restrict__ v_out,
                                  const float* __restrict__ norm_prev,  // 64 slots or null
                                  float* __restrict__ norm_out,         // 64 slots
                                  int n) {
    int lane = threadIdx.x & 63;
    float scale = 1.f;
    if (norm_prev) {
        float x = norm_prev[lane];
#pragma unroll
        for (int off = 32; off; off >>= 1) x += __shfl_xor(x, off, 64);
        scale = 1.f / fmaxf(sqrtf(x), 1e-12f);
    }
    int g = blockIdx.x * 256 + threadIdx.x;
    int row = g >> 1;                   // 2 lanes per row
    int t = g & 1;
    float sq = 0.f;
    if (row < n) {
        int p = row_ptr[row] + t;
        int end = row_ptr[row + 1];
        float s0 = 0.f, s1 = 0.f, s2 = 0.f, s3 = 0.f;
        for (; p + 6 < end; p += 8) {   // 4 independent chains, stride 2
            int2 e0 = cv[p], e1 = cv[p + 2], e2 = cv[p + 4], e3 = cv[p + 6];
            s0 += __int_as_float(e0.y) * v_in[e0.x];
            s1 += __int_as_float(e1.y) * v_in[e1.x];
            s2 += __int_as_float(e2.y) * v_in[e2.x];
            s3 += __int_as_float(e3.y) * v_in[e3.x];
        }
        for (; p < end; p += 2) {
            int2 e = cv[p];
            s0 += __int_as_float(e.y) * v_in[e.x];
        }
        float sv = (s0 + s1) + (s2 + s3);
        sv += __shfl_xor(sv, 1, 2);
        if (t == 0) {
            float sg = (sv > 0.f) ? 1.f : ((sv < 0.f) ? -1.f : 0.f);
            float w = sv * scale - TAU * sg;
            v_out[row] = w;
            sq = w * w;
        }
    }
    for (int off = 32; off; off >>= 1) sq += __shfl_down(sq, off, 64);
    __shared__ float sh[4];
    int wv = threadIdx.x >> 6;
    if (lane == 0) sh[wv] = sq;
    __syncthreads();
    if (threadIdx.x == 0)
        atomicAdd(&norm_out[blockIdx.x & 63], sh[0] + sh[1] + sh[2] + sh[3]);
}

__global__ void finalize_kernel(const float* __restrict__ v,
                                const float* __restrict__ slots,
                                float* __restrict__ out, int n) {
    int lane = threadIdx.x & 63;
    float x = slots[lane];
#pragma unroll
    for (int off = 32; off; off >>= 1) x += __shfl_xor(x, off, 64);
    float inv = 1.f / fmaxf(sqrtf(x), 1e-12f);
    int i = blockIdx.x * 256 + threadIdx.x;
    if (i < n) out[i] = v[i] * inv;
}

extern "C" void kernel_launch(void* const* d_in, const int* in_sizes, int n_in,
                              void* d_out, int out_size, void* d_ws, size_t ws_size,
                              hipStream_t stream) {
    const int* A_row = (const int*)d_in[0];
    const int* A_col = (const int*)d_in[1];
    const float* A_val = (const float*)d_in[2];
    const int* L_row = (const int*)d_in[3];
    const int* L_col = (const int*)d_in[4];
    const float* L_val = (const float*)d_in[5];
    const float* embed = (const float*)d_in[6];
    const float* W1 = (const float*)d_in[7];
    const float* W2 = (const float*)d_in[8];
    const float* Ws = (const float*)d_in[9];
    float* out = (float*)d_out;

    const int E = in_sizes[0];
    const int D = 64;
    const int N = in_sizes[6] / D;
    const int ITERS = 10;
    const int NBC = (N + RPB - 1) / RPB;  // buckets per matrix (391)
    const int NB2 = 2 * NBC;              // 782
    const int cblocks = (E + CHUNK - 1) / CHUNK;  // bin blocks per matrix (196)

    char* ws = (char*)d_ws;
    size_t off = 0;
    auto carve = [&](size_t bytes) {
        void* p = ws + off;
        off += (bytes + 255) & ~(size_t)255;
        return p;
    };
    size_t feat_bytes = (size_t)N * D * sizeof(float);
    size_t tmp_bytes = (size_t)NB2 * SEG * sizeof(int2);   // 28.8 MB
    // X0/X1 and tmp share one region (tmp dead once place ran; X live after)
    char* base = (char*)carve(tmp_bytes > 2 * feat_bytes ? tmp_bytes : 2 * feat_bytes);
    float* X0 = (float*)base;
    float* X1 = (float*)(base + feat_bytes);
    int2* tmp = (int2*)base;
    int* A_rp = (int*)carve((size_t)(N + 1) * sizeof(int));
    int2* A_cv = (int2*)carve((size_t)E * sizeof(int2));
    int* L_rp = (int*)carve((size_t)(N + 1) * sizeof(int));
    int2* L_cv = (int2*)carve((size_t)E * sizeof(int2));
    int* cur = (int*)carve((size_t)NB2 * sizeof(int));
    int* boff = (int*)carve((size_t)NB2 * sizeof(int));
    float* v_cur = (float*)carve((size_t)N * sizeof(float));
    float* v_new = (float*)carve((size_t)N * sizeof(float));
    float* norms = (float*)carve((size_t)ITERS * 64 * sizeof(float));

    // ---- CSR build: block-aggregated counting sort ----
    int imax = NB2 > ITERS * 64 ? NB2 : ITERS * 64;
    init_kernel<<<(imax + 255) / 256, 256, 0, stream>>>(cur, norms, NB2, ITERS * 64);
    bin3_kernel<<<2 * cblocks, 512, 0, stream>>>(A_row, A_col, A_val,
                                                 L_row, L_col, L_val,
                                                 cur, tmp, E, cblocks, NBC);
    scan_kernel<<<1, 1024, 0, stream>>>(cur, boff, NB2);
    place_kernel<<<NB2, 256, 0, stream>>>(cur, boff, tmp,
                                          A_rp, L_rp, A_cv, L_cv, N, NBC);

    // ---- two fused residual GNN layers (layer 2 also emits scores) ----
    // one 4-row group per wave: (N+15)/16 blocks of 4 waves
    int fl_blocks = (N + 15) / 16;
    fused_layer_kernel<<<fl_blocks, 256, 0, stream>>>(
        A_rp, A_cv, embed, W1, X0, nullptr, Ws, N);
    fused_layer_kernel<<<fl_blocks, 256, 0, stream>>>(
        A_rp, A_cv, X0, W2, X1, v_cur, Ws, N);

    // ---- power iterations (normalize folded; 64-slot norm partials) ----
    int p_blocks = (N * 2 + 255) / 256;   // 2 lanes/row
    int n_blocks = (N + 255) / 256;
    float* cur_v = v_cur;
    float* nxt_v = v_new;
    for (int it = 0; it < ITERS; ++it) {
        power_iter_kernel<<<p_blocks, 256, 0, stream>>>(
            L_rp, L_cv, cur_v, nxt_v,
            it ? (norms + (it - 1) * 64) : nullptr, norms + it * 64, N);
        float* t = cur_v; cur_v = nxt_v; nxt_v = t;
    }
    finalize_kernel<<<n_blocks, 256, 0, stream>>>(cur_v, norms + (ITERS - 1) * 64, out, N);
}